// Round 3
// baseline (57832.330 us; speedup 1.0000x reference)
//
#include <hip/hip_runtime.h>
#include <hip/hip_bf16.h>

#define TT 512
#define BB 64
#define HH 128
#define WW 128
#define DD 32
#define NTHR 512
#define NCLUST 32          // clusters; each = 8 member WGs, 2 batches
#define WSTR 132           // padded LDS stride for fp32 weight rows

// LDS floats: w0[128*132] w1[128*132] tss[2*512] ybuf[256] ytmp[256] k1[256] k2[256]
//             h1[256] h2[256] dvec[192] fb2s[512] fb01s[256] idx[8 ints]
#define SMEM_FLOATS (128*WSTR*2 + 2*TT + 256*6 + 192 + 512 + 256 + 8)

typedef __attribute__((ext_vector_type(8))) short short8;
typedef __attribute__((ext_vector_type(4))) float f32x4;

__device__ __forceinline__ float softplus_f(float x) {
    return fmaxf(x, 0.f) + log1pf(__expf(-fabsf(x)));
}
__device__ __forceinline__ float fast_tanh(float x) {
    float ax = fabsf(x);
    float e  = __expf(-2.f * ax);
    float r  = (1.f - e) / (1.f + e);
    return copysignf(r, x);
}
__device__ __forceinline__ short bf16rne(float x) {
    unsigned u = __float_as_uint(x);
    u += 0x7fffu + ((u >> 16) & 1u);
    return (short)(u >> 16);
}

__global__ __launch_bounds__(NTHR, 2)
void cde_kernel(const float* __restrict__ ts,
                const float* __restrict__ cd, const float* __restrict__ cc,
                const float* __restrict__ cb, const float* __restrict__ ca,
                const float* __restrict__ iW0, const float* __restrict__ ib0,
                const float* __restrict__ iW1, const float* __restrict__ ib1,
                const float* __restrict__ iW2, const float* __restrict__ ib2,
                const float* __restrict__ fW0, const float* __restrict__ fb0,
                const float* __restrict__ fW1, const float* __restrict__ fb1,
                const float* __restrict__ fW2, const float* __restrict__ fb2,
                const float* __restrict__ lW, const float* __restrict__ lb,
                float* __restrict__ kbuf, unsigned* __restrict__ ctrs,
                float* __restrict__ out)
{
    extern __shared__ float sm[];
    float* w0    = sm;
    float* w1    = w0 + 128 * WSTR;
    float* tssm  = w1 + 128 * WSTR;   // [2][512]
    float* ybuf  = tssm + 2 * TT;     // [2][128]
    float* ytmp  = ybuf + 256;
    float* k1b   = ytmp + 256;
    float* k2b   = k1b + 256;
    float* h1b   = k2b + 256;
    float* h2b   = h1b + 256;
    float* dvecs = h2b + 256;         // [2][96]
    float* fb2s  = dvecs + 192;       // [512] member slice of fb2
    float* fb0s  = fb2s + 512;        // [128]
    float* fb1s  = fb0s + 128;        // [128]
    int*   idxb  = (int*)(fb1s + 128); // [6]

    const int tid  = threadIdx.x;
    const int lane = tid & 63;
    const int wv   = tid >> 6;              // 0..7
    const int c    = blockIdx.x & (NCLUST - 1);   // cluster (XCD-colocated: ids ≡ c mod 8)
    const int m    = blockIdx.x >> 5;             // member 0..7
    const int b0   = 2 * c;                       // batches b0, b0+1

    // ---- stage LDS: w0/w1 fp32 padded, ts, biases ----
    for (int i = tid; i < WW * HH; i += NTHR) {
        int r = i >> 7, cc2 = i & 127;
        w0[r * WSTR + cc2] = fW0[i];
        w1[r * WSTR + cc2] = fW1[i];
    }
    for (int i = tid; i < 2 * TT; i += NTHR) {
        int bb = i >> 9, j = i & 511;
        tssm[i] = ts[(size_t)(b0 + bb) * TT + j];
    }
    for (int i = tid; i < 512; i += NTHR) fb2s[i] = fb2[m * 512 + i];
    for (int i = tid; i < 128; i += NTHR) { fb0s[i] = fb0[i]; fb1s[i] = fb1[i]; }

    // ---- register-resident W2 A-fragments (loop-invariant!) ----
    // wave owns h-groups g0, g0+1 (32 rows each); 8 frags per group (2 tiles x 4 K)
    const int g0 = m * 16 + wv * 2;
    short8 afr[2][8];
    #pragma unroll
    for (int gi = 0; gi < 2; ++gi) {
        int g = g0 + gi;
        #pragma unroll
        for (int t = 0; t < 2; ++t)
        #pragma unroll
        for (int K = 0; K < 4; ++K) {
            int row = g * 32 + t * 16 + (lane & 15);
            int col = K * 32 + (lane >> 4) * 8;
            const float* src = fW2 + (size_t)row * WW + col;
            short8 v;
            #pragma unroll
            for (int j = 0; j < 8; ++j) v[j] = bf16rne(src[j]);
            afr[gi][t * 4 + K] = v;
        }
    }
    __syncthreads();

    const float dt0 = tssm[1] - tssm[0];
    const float dt1 = tssm[TT + 1] - tssm[TT];
    float t00 = tssm[0];
    float t01 = tssm[TT];

    const size_t cstride = (size_t)(TT - 1) * DD;

    // ---- initial_mlp (replicated per WG, both batches), one-time ----
    if (tid < 256) {
        int bb = tid >> 7, row = tid & 127;
        const float* a0 = ca + (size_t)(b0 + bb) * cstride;
        float acc = ib0[row];
        #pragma unroll
        for (int k = 0; k < DD; ++k) acc += iW0[row * DD + k] * a0[k];
        h1b[tid] = fmaxf(acc, 0.f);
    }
    __syncthreads();
    if (tid < 256) {
        int bb = tid >> 7, row = tid & 127;
        float acc = ib1[row];
        for (int k = 0; k < WW; ++k) acc += iW1[row * WW + k] * h1b[bb * 128 + k];
        h2b[tid] = fmaxf(acc, 0.f);
    }
    __syncthreads();
    if (tid < 256) {
        int bb = tid >> 7, row = tid & 127;
        float acc = ib2[row];
        for (int k = 0; k < WW; ++k) acc += iW2[row * WW + k] * h2b[bb * 128 + k];
        ybuf[tid] = acc;
    }
    __syncthreads();

    float lwa = 0.f, lwb = 0.f, lbv = 0.f;
    if (wv < 2) { lwa = lW[lane]; lwb = lW[64 + lane]; lbv = lb[0]; }

    const float* cdb0 = cd + (size_t)b0 * cstride;
    const float* ccb0 = cc + (size_t)b0 * cstride;
    const float* cbb0 = cb + (size_t)b0 * cstride;

    unsigned* ctr = ctrs + c * 16;
    unsigned mygen = 0;

    for (int s = 0; s < TT; ++s) {
        // ---- searchsorted via per-wave ballots (waves 0,1 = batches 0,1) ----
        if (wv < 2) {
            float tb  = wv ? t01 : t00;
            float dtb = wv ? dt1 : dt0;
            float tv0 = tb, tv1 = tb + 0.5f * dtb, tv2 = tb + 0.75f * dtb;
            int c0 = 0, c1 = 0, c2 = 0;
            const float* tw = tssm + wv * TT;
            #pragma unroll
            for (int ch = 0; ch < 8; ++ch) {
                float v = tw[ch * 64 + lane];
                c0 += __popcll(__ballot(v <= tv0));
                c1 += __popcll(__ballot(v <= tv1));
                c2 += __popcll(__ballot(v <= tv2));
            }
            if (lane == 0) {
                idxb[wv * 3 + 0] = min(max(c0 - 1, 0), TT - 2);
                idxb[wv * 3 + 1] = min(max(c1 - 1, 0), TT - 2);
                idxb[wv * 3 + 2] = min(max(c2 - 1, 0), TT - 2);
            }
        }
        __syncthreads();

        const float* yin = ybuf;
        #pragma unroll 1
        for (int q = 0; q < 3; ++q) {
            const int buf = (s * 3 + q) & 1;
            // ---- h1 = softplus(w0 @ yin + fb0): 2 lanes/output, 4-way-max banks ----
            {
                int o = tid >> 1, bb = o >> 7, row = o & 127, hh = tid & 1;
                const float* wr = w0 + row * WSTR;
                const float* xr = yin + bb * 128;
                float acc = 0.f;
                #pragma unroll
                for (int jj = 0; jj < 4; ++jj) {
                    int sg = (hh + 2 * jj) * 16;
                    #pragma unroll
                    for (int mm = 0; mm < 4; ++mm) {
                        float4 a = *(const float4*)(wr + sg + mm * 4);
                        float4 x = *(const float4*)(xr + sg + mm * 4);
                        acc += a.x * x.x + a.y * x.y + a.z * x.z + a.w * x.w;
                    }
                }
                acc += __shfl_xor(acc, 1);
                if (hh == 0) h1b[o] = softplus_f(acc + fb0s[row]);
            }
            if (q == 0 && tid < 192) {  // dvec for all 3 RK stages, both batches
                int bb = tid / 96, u = tid % 96, qq = u >> 5, d = u & 31;
                int idx = idxb[bb * 3 + qq];
                float tb  = bb ? t01 : t00;
                float dtb = bb ? dt1 : dt0;
                float tv  = tb + ((qq == 0) ? 0.f : (qq == 1) ? 0.5f : 0.75f) * dtb;
                float frac = tv - tssm[bb * TT + idx];
                size_t o = (size_t)idx * DD + d;
                size_t boff = (size_t)bb * cstride;
                dvecs[bb * 96 + qq * 32 + d] =
                    cbb0[boff + o] + frac * (2.f * ccb0[boff + o] + frac * 3.f * cdb0[boff + o]);
            }
            __syncthreads();
            // ---- h2 = softplus(w1 @ h1 + fb1) ----
            {
                int o = tid >> 1, bb = o >> 7, row = o & 127, hh = tid & 1;
                const float* wr = w1 + row * WSTR;
                const float* xr = h1b + bb * 128;
                float acc = 0.f;
                #pragma unroll
                for (int jj = 0; jj < 4; ++jj) {
                    int sg = (hh + 2 * jj) * 16;
                    #pragma unroll
                    for (int mm = 0; mm < 4; ++mm) {
                        float4 a = *(const float4*)(wr + sg + mm * 4);
                        float4 x = *(const float4*)(xr + sg + mm * 4);
                        acc += a.x * x.x + a.y * x.y + a.z * x.z + a.w * x.w;
                    }
                }
                acc += __shfl_xor(acc, 1);
                if (hh == 0) h2b[o] = softplus_f(acc + fb1s[row]);
            }
            __syncthreads();

            // ---- MFMA on register-resident W2; B cols 0-7 = batch0, 8-15 = batch1 ----
            {
                const int kb = (lane >> 4) * 8;
                const int bb = (lane & 15) >> 3;
                const float dtb = bb ? dt1 : dt0;
                short8 bfr[4];
                #pragma unroll
                for (int K = 0; K < 4; ++K) {
                    #pragma unroll
                    for (int j = 0; j < 8; ++j)
                        bfr[K][j] = bf16rne(h2b[bb * 128 + K * 32 + kb + j]);
                }
                const int quad = lane >> 4;
                const float* dv = dvecs + bb * 96 + q * 32;
                #pragma unroll
                for (int gi = 0; gi < 2; ++gi) {
                    f32x4 a0 = {0.f, 0.f, 0.f, 0.f};
                    f32x4 a1 = {0.f, 0.f, 0.f, 0.f};
                    a0 = __builtin_amdgcn_mfma_f32_16x16x32_bf16(afr[gi][0], bfr[0], a0, 0, 0, 0);
                    a0 = __builtin_amdgcn_mfma_f32_16x16x32_bf16(afr[gi][1], bfr[1], a0, 0, 0, 0);
                    a0 = __builtin_amdgcn_mfma_f32_16x16x32_bf16(afr[gi][2], bfr[2], a0, 0, 0, 0);
                    a0 = __builtin_amdgcn_mfma_f32_16x16x32_bf16(afr[gi][3], bfr[3], a0, 0, 0, 0);
                    a1 = __builtin_amdgcn_mfma_f32_16x16x32_bf16(afr[gi][4], bfr[0], a1, 0, 0, 0);
                    a1 = __builtin_amdgcn_mfma_f32_16x16x32_bf16(afr[gi][5], bfr[1], a1, 0, 0, 0);
                    a1 = __builtin_amdgcn_mfma_f32_16x16x32_bf16(afr[gi][6], bfr[2], a1, 0, 0, 0);
                    a1 = __builtin_amdgcn_mfma_f32_16x16x32_bf16(afr[gi][7], bfr[3], a1, 0, 0, 0);
                    // C/D: col=lane&15, row=quad*4+reg; t=0 → d 0-15, t=1 → d 16-31
                    const float* fb = fb2s + (wv * 2 + gi) * 32;
                    float part = 0.f;
                    #pragma unroll
                    for (int r = 0; r < 4; ++r) {
                        int d = quad * 4 + r;
                        part += fast_tanh(a0[r] + fb[d]) * dv[d];
                        part += fast_tanh(a1[r] + fb[16 + d]) * dv[16 + d];
                    }
                    part += __shfl_xor(part, 16);
                    part += __shfl_xor(part, 32);
                    if ((lane & 15) == 0) {
                        int g = g0 + gi;
                        __hip_atomic_store(&kbuf[(size_t)(buf * BB + b0 + bb) * HH + g],
                                           part * dtb, __ATOMIC_RELAXED,
                                           __HIP_MEMORY_SCOPE_AGENT);
                    }
                }
            }
            // ---- cluster barrier (8 WGs, same XCD by swizzle; agent-scope) ----
            __threadfence();
            __syncthreads();
            ++mygen;
            if (tid == 0) {
                __hip_atomic_fetch_add(ctr, 1u, __ATOMIC_ACQ_REL, __HIP_MEMORY_SCOPE_AGENT);
                unsigned tgt = 8u * mygen;
                while (__hip_atomic_load(ctr, __ATOMIC_ACQUIRE, __HIP_MEMORY_SCOPE_AGENT) < tgt)
                    __builtin_amdgcn_s_sleep(1);
            }
            __syncthreads();
            // ---- y update (replicated) ----
            if (tid < 256) {
                int bb = tid >> 7;
                float kv = __hip_atomic_load(&kbuf[(size_t)(buf * BB + b0 + bb) * HH + (tid & 127)],
                                             __ATOMIC_RELAXED, __HIP_MEMORY_SCOPE_AGENT);
                float dtb = bb ? dt1 : dt0;
                if (q == 0)      { k1b[tid] = kv; ytmp[tid] = ybuf[tid] + 0.5f  * kv; }
                else if (q == 1) { k2b[tid] = kv; ytmp[tid] = ybuf[tid] + 0.75f * kv; }
                else ybuf[tid] += dtb * ((2.f/9.f) * k1b[tid] + (1.f/3.f) * k2b[tid] + (4.f/9.f) * kv);
            }
            __syncthreads();
            yin = ytmp;
        }

        // ---- readout (member 0 only; waves 0,1 = batches) ----
        if (m == 0 && wv < 2) {
            float p = ybuf[wv * 128 + lane] * lwa + ybuf[wv * 128 + 64 + lane] * lwb;
            p += __shfl_xor(p, 1);  p += __shfl_xor(p, 2);  p += __shfl_xor(p, 4);
            p += __shfl_xor(p, 8);  p += __shfl_xor(p, 16); p += __shfl_xor(p, 32);
            if (lane == 0) out[(size_t)(b0 + wv) * TT + s] = 1.f / (1.f + __expf(-(p + lbv)));
        }
        t00 += dt0; t01 += dt1;
    }
}

extern "C" void kernel_launch(void* const* d_in, const int* in_sizes, int n_in,
                              void* d_out, int out_size, void* d_ws, size_t ws_size,
                              hipStream_t stream) {
    const float* ts  = (const float*)d_in[0];
    const float* cdp = (const float*)d_in[1];
    const float* ccp = (const float*)d_in[2];
    const float* cbp = (const float*)d_in[3];
    const float* cap = (const float*)d_in[4];
    const float* iW0 = (const float*)d_in[5];
    const float* ib0 = (const float*)d_in[6];
    const float* iW1 = (const float*)d_in[7];
    const float* ib1 = (const float*)d_in[8];
    const float* iW2 = (const float*)d_in[9];
    const float* ib2 = (const float*)d_in[10];
    const float* fW0 = (const float*)d_in[11];
    const float* fb0 = (const float*)d_in[12];
    const float* fW1 = (const float*)d_in[13];
    const float* fb1 = (const float*)d_in[14];
    const float* fW2 = (const float*)d_in[15];
    const float* fb2 = (const float*)d_in[16];
    const float* lW  = (const float*)d_in[17];
    const float* lb  = (const float*)d_in[18];
    float* out = (float*)d_out;

    float*    kbuf = (float*)d_ws;                    // [2][64][128] fp32 = 64 KiB
    unsigned* ctrs = (unsigned*)((char*)d_ws + 65536); // 32 clusters x 64 B

    hipMemsetAsync(d_ws, 0, 65536 + 2048, stream);

    const size_t smem_bytes = SMEM_FLOATS * sizeof(float);
    hipFuncSetAttribute((const void*)cde_kernel,
                        hipFuncAttributeMaxDynamicSharedMemorySize, (int)smem_bytes);
    hipLaunchKernelGGL(cde_kernel, dim3(256), dim3(NTHR), smem_bytes, stream,
                       ts, cdp, ccp, cbp, cap, iW0, ib0, iW1, ib1, iW2, ib2,
                       fW0, fb0, fW1, fb1, fW2, fb2, lW, lb, kbuf, ctrs, out);
}

// Round 4
// 9400.941 us; speedup vs baseline: 6.1518x; 6.1518x over previous
//
#include <hip/hip_runtime.h>
#include <hip/hip_bf16.h>

#define TT 512
#define BB 64
#define HH 128
#define WW 128
#define DD 32
#define NTHR 512
#define WSTR 132   // padded LDS stride for fp32 weight rows

// LDS floats: w0[128*132] w1[128*132] tss[512] ybuf/ytmp/k1/k2/h1/h2[128 each]
//             dvec[96] fb2s[1024] fb0s[128] fb1s[128] idx[8]
#define SMEM_FLOATS (128*WSTR*2 + TT + 128*6 + 96 + 1024 + 256 + 8)

typedef __attribute__((ext_vector_type(8))) short short8;
typedef __attribute__((ext_vector_type(4))) float f32x4;

__device__ __forceinline__ float softplus_f(float x) {
    return fmaxf(x, 0.f) + log1pf(__expf(-fabsf(x)));
}
__device__ __forceinline__ float fast_tanh(float x) {
    float ax = fabsf(x);
    float e  = __expf(-2.f * ax);
    float r  = (1.f - e) / (1.f + e);
    return copysignf(r, x);
}
__device__ __forceinline__ short bf16rne(float x) {
    unsigned u = __float_as_uint(x);
    u += 0x7fffu + ((u >> 16) & 1u);
    return (short)(u >> 16);
}

__global__ __launch_bounds__(NTHR, 2)
void cde_kernel(const float* __restrict__ ts,
                const float* __restrict__ cd, const float* __restrict__ cc,
                const float* __restrict__ cb, const float* __restrict__ ca,
                const float* __restrict__ iW0, const float* __restrict__ ib0,
                const float* __restrict__ iW1, const float* __restrict__ ib1,
                const float* __restrict__ iW2, const float* __restrict__ ib2,
                const float* __restrict__ fW0, const float* __restrict__ fb0,
                const float* __restrict__ fW1, const float* __restrict__ fb1,
                const float* __restrict__ fW2, const float* __restrict__ fb2,
                const float* __restrict__ lW, const float* __restrict__ lb,
                unsigned long long* kbuf,
                float* __restrict__ out)
{
    extern __shared__ float sm[];
    float* w0    = sm;
    float* w1    = w0 + 128 * WSTR;
    float* tss   = w1 + 128 * WSTR;   // [512]
    float* ybuf  = tss + TT;          // [128]
    float* ytmp  = ybuf + 128;
    float* k1b   = ytmp + 128;
    float* k2b   = k1b + 128;
    float* h1b   = k2b + 128;
    float* h2b   = h1b + 128;
    float* dvec  = h2b + 128;         // [96]
    float* fb2s  = dvec + 96;         // [1024] member slice of fb2
    float* fb0s  = fb2s + 1024;       // [128]
    float* fb1s  = fb0s + 128;        // [128]
    int*   idxb  = (int*)(fb1s + 128); // [3]

    const int tid  = threadIdx.x;
    const int lane = tid & 63;
    const int wv   = tid >> 6;              // 0..7
    const int b    = blockIdx.x & 63;       // batch; members share b -> same XCD class
    const int m    = blockIdx.x >> 6;       // member 0..3

    // ---- stage LDS: w0/w1 fp32 padded, ts, biases ----
    for (int i = tid; i < WW * HH; i += NTHR) {
        int r = i >> 7, c2 = i & 127;
        w0[r * WSTR + c2] = fW0[i];
        w1[r * WSTR + c2] = fW1[i];
    }
    for (int i = tid; i < TT; i += NTHR)   tss[i]  = ts[(size_t)b * TT + i];
    for (int i = tid; i < 1024; i += NTHR) fb2s[i] = fb2[m * 1024 + i];
    for (int i = tid; i < 128; i += NTHR)  { fb0s[i] = fb0[i]; fb1s[i] = fb1[i]; }

    // ---- register-resident W2 A-fragments (loop-invariant) ----
    // wave owns groups g = m*32 + wv*4 + gi, gi=0..3; each = 32 W2 rows (h=g, d=0..31)
    short8 afr[4][8];
    #pragma unroll
    for (int gi = 0; gi < 4; ++gi) {
        int g = m * 32 + wv * 4 + gi;
        #pragma unroll
        for (int t = 0; t < 2; ++t)
        #pragma unroll
        for (int K = 0; K < 4; ++K) {
            int row = g * 32 + t * 16 + (lane & 15);
            int col = K * 32 + (lane >> 4) * 8;
            const float* src = fW2 + (size_t)row * WW + col;
            short8 v;
            #pragma unroll
            for (int j = 0; j < 8; ++j) v[j] = bf16rne(src[j]);
            afr[gi][t * 4 + K] = v;
        }
    }
    __syncthreads();

    const float dt = tss[1] - tss[0];
    float t00 = tss[0];
    const size_t cstride = (size_t)(TT - 1) * DD;
    const float* cdb = cd + (size_t)b * cstride;
    const float* ccb = cc + (size_t)b * cstride;
    const float* cbb = cb + (size_t)b * cstride;

    // ---- initial_mlp (replicated per member), one-time ----
    if (tid < HH) {
        const float* a0 = ca + (size_t)b * cstride;
        float acc = ib0[tid];
        #pragma unroll
        for (int k = 0; k < DD; ++k) acc += iW0[tid * DD + k] * a0[k];
        h1b[tid] = fmaxf(acc, 0.f);
    }
    __syncthreads();
    if (tid < HH) {
        float acc = ib1[tid];
        for (int k = 0; k < WW; ++k) acc += iW1[tid * WW + k] * h1b[k];
        h2b[tid] = fmaxf(acc, 0.f);
    }
    __syncthreads();
    if (tid < HH) {
        float acc = ib2[tid];
        for (int k = 0; k < WW; ++k) acc += iW2[tid * WW + k] * h2b[k];
        ybuf[tid] = acc;
    }
    __syncthreads();

    float lwa = 0.f, lwb = 0.f, lbv = 0.f;
    if (wv == 0) { lwa = lW[lane]; lwb = lW[64 + lane]; lbv = lb[0]; }

    const int sub = tid & 3;        // 4 lanes per output row in h1/h2
    const int orow = tid >> 2;      // 0..127

    for (int s = 0; s < TT; ++s) {
        // ---- searchsorted via wave-0 ballots ----
        if (wv == 0) {
            float tv0 = t00, tv1 = t00 + 0.5f * dt, tv2 = t00 + 0.75f * dt;
            int c0 = 0, c1 = 0, c2 = 0;
            #pragma unroll
            for (int ch = 0; ch < 8; ++ch) {
                float v = tss[ch * 64 + lane];
                c0 += __popcll(__ballot(v <= tv0));
                c1 += __popcll(__ballot(v <= tv1));
                c2 += __popcll(__ballot(v <= tv2));
            }
            if (lane == 0) {
                idxb[0] = min(max(c0 - 1, 0), TT - 2);
                idxb[1] = min(max(c1 - 1, 0), TT - 2);
                idxb[2] = min(max(c2 - 1, 0), TT - 2);
            }
        }
        __syncthreads();

        const float* yin = ybuf;
        #pragma unroll 1
        for (int q = 0; q < 3; ++q) {
            const int gen = s * 3 + q + 1;
            const int buf = gen & 1;
            // ---- h1 = softplus(w0 @ yin + fb0): 4 lanes/row, interleaved cols ----
            {
                const float* wr = w0 + orow * WSTR;
                float acc = 0.f;
                #pragma unroll
                for (int j = 0; j < 8; ++j) {
                    int col = (j * 4 + sub) * 4;
                    float4 a = *(const float4*)(wr + col);
                    float4 x = *(const float4*)(yin + col);
                    acc += a.x * x.x + a.y * x.y + a.z * x.z + a.w * x.w;
                }
                acc += __shfl_xor(acc, 1); acc += __shfl_xor(acc, 2);
                if (sub == 0) h1b[orow] = softplus_f(acc + fb0s[orow]);
            }
            if (q == 0 && tid < 96) {   // dvec for all 3 RK stages
                int qq = tid >> 5, d = tid & 31;
                int idx = idxb[qq];
                float tv = t00 + ((qq == 0) ? 0.f : (qq == 1) ? 0.5f : 0.75f) * dt;
                float frac = tv - tss[idx];
                size_t o = (size_t)idx * DD + d;
                dvec[qq * 32 + d] = cbb[o] + frac * (2.f * ccb[o] + frac * 3.f * cdb[o]);
            }
            __syncthreads();
            // ---- h2 = softplus(w1 @ h1 + fb1) ----
            {
                const float* wr = w1 + orow * WSTR;
                float acc = 0.f;
                #pragma unroll
                for (int j = 0; j < 8; ++j) {
                    int col = (j * 4 + sub) * 4;
                    float4 a = *(const float4*)(wr + col);
                    float4 x = *(const float4*)(h1b + col);
                    acc += a.x * x.x + a.y * x.y + a.z * x.z + a.w * x.w;
                }
                acc += __shfl_xor(acc, 1); acc += __shfl_xor(acc, 2);
                if (sub == 0) h2b[orow] = softplus_f(acc + fb1s[orow]);
            }
            __syncthreads();

            // ---- MFMA on register-resident W2, tanh + D-contract ----
            {
                const int kb = (lane >> 4) * 8;
                const int quad = lane >> 4;
                short8 bfr[4];
                #pragma unroll
                for (int K = 0; K < 4; ++K) {
                    #pragma unroll
                    for (int j = 0; j < 8; ++j) bfr[K][j] = bf16rne(h2b[K * 32 + kb + j]);
                }
                const float* dv = dvec + q * 32;
                float kreg = 0.f;
                #pragma unroll
                for (int gi = 0; gi < 4; ++gi) {
                    f32x4 a0 = {0.f, 0.f, 0.f, 0.f};
                    f32x4 a1 = {0.f, 0.f, 0.f, 0.f};
                    a0 = __builtin_amdgcn_mfma_f32_16x16x32_bf16(afr[gi][0], bfr[0], a0, 0, 0, 0);
                    a0 = __builtin_amdgcn_mfma_f32_16x16x32_bf16(afr[gi][1], bfr[1], a0, 0, 0, 0);
                    a0 = __builtin_amdgcn_mfma_f32_16x16x32_bf16(afr[gi][2], bfr[2], a0, 0, 0, 0);
                    a0 = __builtin_amdgcn_mfma_f32_16x16x32_bf16(afr[gi][3], bfr[3], a0, 0, 0, 0);
                    a1 = __builtin_amdgcn_mfma_f32_16x16x32_bf16(afr[gi][4], bfr[0], a1, 0, 0, 0);
                    a1 = __builtin_amdgcn_mfma_f32_16x16x32_bf16(afr[gi][5], bfr[1], a1, 0, 0, 0);
                    a1 = __builtin_amdgcn_mfma_f32_16x16x32_bf16(afr[gi][6], bfr[2], a1, 0, 0, 0);
                    a1 = __builtin_amdgcn_mfma_f32_16x16x32_bf16(afr[gi][7], bfr[3], a1, 0, 0, 0);
                    // C/D: col=lane&15, row=quad*4+reg (all 16 cols identical here)
                    const float* fb = fb2s + (wv * 4 + gi) * 32;
                    float part = 0.f;
                    #pragma unroll
                    for (int r = 0; r < 4; ++r) {
                        int d = quad * 4 + r;
                        part += fast_tanh(a0[r] + fb[d]) * dv[d];
                        part += fast_tanh(a1[r] + fb[16 + d]) * dv[16 + d];
                    }
                    part += __shfl_xor(part, 16);
                    part += __shfl_xor(part, 32);
                    if (lane == gi) kreg = part * dt;   // k value for group g0+gi
                }
                // ---- fence-free publish: (f32 bits << 32) | gen, relaxed atomic ----
                if (lane < 4) {
                    int g = m * 32 + wv * 4 + lane;
                    unsigned long long pk =
                        ((unsigned long long)__float_as_uint(kreg) << 32) | (unsigned)gen;
                    __hip_atomic_store(&kbuf[(size_t)(buf * BB + b) * HH + g], pk,
                                       __ATOMIC_RELAXED, __HIP_MEMORY_SCOPE_AGENT);
                }
            }
            // ---- poll foreign k-values (tag == gen means data valid; no fences) ----
            if (tid < HH) {
                unsigned long long v;
                for (;;) {
                    v = __hip_atomic_load(&kbuf[(size_t)(buf * BB + b) * HH + tid],
                                          __ATOMIC_RELAXED, __HIP_MEMORY_SCOPE_AGENT);
                    if ((unsigned)v == (unsigned)gen) break;
                    __builtin_amdgcn_s_sleep(1);
                }
                float kv = __uint_as_float((unsigned)(v >> 32));
                if (q == 0)      { k1b[tid] = kv; ytmp[tid] = ybuf[tid] + 0.5f  * kv; }
                else if (q == 1) { k2b[tid] = kv; ytmp[tid] = ybuf[tid] + 0.75f * kv; }
                else ybuf[tid] += dt * ((2.f/9.f) * k1b[tid] + (1.f/3.f) * k2b[tid] + (4.f/9.f) * kv);
            }
            __syncthreads();
            yin = ytmp;
        }

        // ---- readout (member 0, wave 0) ----
        if (m == 0 && wv == 0) {
            float p = ybuf[lane] * lwa + ybuf[64 + lane] * lwb;
            p += __shfl_xor(p, 1);  p += __shfl_xor(p, 2);  p += __shfl_xor(p, 4);
            p += __shfl_xor(p, 8);  p += __shfl_xor(p, 16); p += __shfl_xor(p, 32);
            if (lane == 0) out[(size_t)b * TT + s] = 1.f / (1.f + __expf(-(p + lbv)));
        }
        t00 += dt;
    }
}

extern "C" void kernel_launch(void* const* d_in, const int* in_sizes, int n_in,
                              void* d_out, int out_size, void* d_ws, size_t ws_size,
                              hipStream_t stream) {
    const float* ts  = (const float*)d_in[0];
    const float* cdp = (const float*)d_in[1];
    const float* ccp = (const float*)d_in[2];
    const float* cbp = (const float*)d_in[3];
    const float* cap = (const float*)d_in[4];
    const float* iW0 = (const float*)d_in[5];
    const float* ib0 = (const float*)d_in[6];
    const float* iW1 = (const float*)d_in[7];
    const float* ib1 = (const float*)d_in[8];
    const float* iW2 = (const float*)d_in[9];
    const float* ib2 = (const float*)d_in[10];
    const float* fW0 = (const float*)d_in[11];
    const float* fb0 = (const float*)d_in[12];
    const float* fW1 = (const float*)d_in[13];
    const float* fb1 = (const float*)d_in[14];
    const float* fW2 = (const float*)d_in[15];
    const float* fb2 = (const float*)d_in[16];
    const float* lW  = (const float*)d_in[17];
    const float* lb  = (const float*)d_in[18];
    float* out = (float*)d_out;

    unsigned long long* kbuf = (unsigned long long*)d_ws;  // [2][64][128] u64 = 128 KiB
    hipMemsetAsync(d_ws, 0, 2 * BB * HH * sizeof(unsigned long long), stream);

    const size_t smem_bytes = SMEM_FLOATS * sizeof(float);
    hipFuncSetAttribute((const void*)cde_kernel,
                        hipFuncAttributeMaxDynamicSharedMemorySize, (int)smem_bytes);
    hipLaunchKernelGGL(cde_kernel, dim3(256), dim3(NTHR), smem_bytes, stream,
                       ts, cdp, ccp, cbp, cap, iW0, ib0, iW1, ib1, iW2, ib2,
                       fW0, fb0, fW1, fb1, fW2, fb2, lW, lb, kbuf, out);
}

// Round 5
// 8196.070 us; speedup vs baseline: 7.0561x; 1.1470x over previous
//
#include <hip/hip_runtime.h>
#include <hip/hip_bf16.h>

#define TT 512
#define BB 64
#define HH 128
#define WW 128
#define DD 32
#define NTHR 512
#define RSTR 40          // rowbuf stride (floats): 16B-aligned rows, ≤2-way banks in epilogue

// LDS floats actually used: tss[512] ybuf[128] k1b[128] k2b[128] rowbuf[32*40]
//   dvec[96] fb2s[1024] + bf16: ybf[128] h1bf[128] h2bf[128] (=192 floats)
// Requested LDS is padded to 84 KiB to force exactly 1 WG/CU (even member spread).
#define SMEM_BYTES 86016

typedef __attribute__((ext_vector_type(8))) short short8;
typedef __attribute__((ext_vector_type(4))) float f32x4;

__device__ __forceinline__ float softplus_f(float x) {
    return fmaxf(x, 0.f) + log1pf(__expf(-fabsf(x)));
}
__device__ __forceinline__ float fast_tanh(float x) {
    float ax = fabsf(x);
    float e  = __expf(-2.f * ax);
    float r  = (1.f - e) / (1.f + e);
    return copysignf(r, x);
}
__device__ __forceinline__ short bf16rne(float x) {
    unsigned u = __float_as_uint(x);
    u += 0x7fffu + ((u >> 16) & 1u);
    return (short)(u >> 16);
}

__global__ __launch_bounds__(NTHR, 2)
void cde_kernel(const float* __restrict__ ts,
                const float* __restrict__ cd, const float* __restrict__ cc,
                const float* __restrict__ cb, const float* __restrict__ ca,
                const float* __restrict__ iW0, const float* __restrict__ ib0,
                const float* __restrict__ iW1, const float* __restrict__ ib1,
                const float* __restrict__ iW2, const float* __restrict__ ib2,
                const float* __restrict__ fW0, const float* __restrict__ fb0,
                const float* __restrict__ fW1, const float* __restrict__ fb1,
                const float* __restrict__ fW2, const float* __restrict__ fb2,
                const float* __restrict__ lW, const float* __restrict__ lb,
                unsigned long long* kbuf,
                float* __restrict__ out)
{
    extern __shared__ float sm[];
    float* tss    = sm;                 // [512]
    float* ybuf   = tss + TT;           // [128] fp32 state
    float* k1b    = ybuf + 128;         // [128]
    float* k2b    = k1b + 128;          // [128]
    float* rowbuf = k2b + 128;          // [32][RSTR]
    float* dvec   = rowbuf + 32 * RSTR; // [96]
    float* fb2s   = dvec + 96;          // [1024] member slice of fb2
    short* ybf    = (short*)(fb2s + 1024); // [128] bf16 stage input
    short* h1bf   = ybf + 128;          // [128]
    short* h2bf   = h1bf + 128;         // [128]
    float* scr    = rowbuf;             // init-MLP scratch (256 floats)

    const int tid  = threadIdx.x;
    const int lane = tid & 63;
    const int wv   = tid >> 6;               // 0..7
    const int quad = lane >> 4;              // 0..3
    const int qr   = lane & 15;              // 0..15
    const int b    = blockIdx.x & 63;        // batch; members ≡ b (mod 8) → same XCD
    const int m    = blockIdx.x >> 6;        // member 0..3

    for (int i = tid; i < TT; i += NTHR)   tss[i]  = ts[(size_t)b * TT + i];
    for (int i = tid; i < 1024; i += NTHR) fb2s[i] = fb2[m * 1024 + i];

    // ---- register-resident weights (loop-invariant, bf16 A-fragments) ----
    // W2: wave owns h = m*32 + wv*4 + gi (gi=0..3); frag[t*4+K] covers rows
    //     h*32 + t*16 + qr of flattened [4096], k = K*32 + quad*8 + j.
    short8 afr[4][8];
    #pragma unroll
    for (int gi = 0; gi < 4; ++gi) {
        int g = m * 32 + wv * 4 + gi;
        #pragma unroll
        for (int t = 0; t < 2; ++t)
        #pragma unroll
        for (int K = 0; K < 4; ++K) {
            int row = g * 32 + t * 16 + qr;
            int col = K * 32 + quad * 8;
            const float* src = fW2 + (size_t)row * WW + col;
            short8 v;
            #pragma unroll
            for (int j = 0; j < 8; ++j) v[j] = bf16rne(src[j]);
            afr[gi][t * 4 + K] = v;
        }
    }
    // W0/W1: wave owns output row-tile wv (rows wv*16 .. +15)
    short8 w0f[4], w1f[4];
    #pragma unroll
    for (int K = 0; K < 4; ++K) {
        int row = wv * 16 + qr;
        int col = K * 32 + quad * 8;
        const float* s0 = fW0 + (size_t)row * HH + col;
        const float* s1 = fW1 + (size_t)row * WW + col;
        short8 v0, v1;
        #pragma unroll
        for (int j = 0; j < 8; ++j) { v0[j] = bf16rne(s0[j]); v1[j] = bf16rne(s1[j]); }
        w0f[K] = v0; w1f[K] = v1;
    }
    // epilogue biases for this lane's rows (wv*16 + quad*4 .. +3)
    float4 fb0v = *(const float4*)(fb0 + wv * 16 + quad * 4);
    float4 fb1v = *(const float4*)(fb1 + wv * 16 + quad * 4);

    __syncthreads();

    const float dt = tss[1] - tss[0];
    float t00 = tss[0];
    const size_t cstride = (size_t)(TT - 1) * DD;
    const float* cdb = cd + (size_t)b * cstride;
    const float* ccb = cc + (size_t)b * cstride;
    const float* cbb = cb + (size_t)b * cstride;

    // ---- initial_mlp (replicated per member, one-time, fp32) ----
    if (tid < HH) {
        const float* a0 = ca + (size_t)b * cstride;
        float acc = ib0[tid];
        #pragma unroll
        for (int k = 0; k < DD; ++k) acc += iW0[tid * DD + k] * a0[k];
        scr[tid] = fmaxf(acc, 0.f);
    }
    __syncthreads();
    if (tid < HH) {
        float acc = ib1[tid];
        for (int k = 0; k < WW; ++k) acc += iW1[tid * WW + k] * scr[k];
        scr[128 + tid] = fmaxf(acc, 0.f);
    }
    __syncthreads();
    if (tid < HH) {
        float acc = ib2[tid];
        for (int k = 0; k < WW; ++k) acc += iW2[tid * WW + k] * scr[128 + k];
        ybuf[tid] = acc;
        ybf[tid]  = bf16rne(acc);
    }
    __syncthreads();

    float lwa = 0.f, lwb = 0.f, lbv = 0.f;
    if (wv == 0) { lwa = lW[lane]; lwb = lW[64 + lane]; lbv = lb[0]; }

    for (int s = 0; s < TT; ++s) {
        // ---- searchsorted + dvec: waves 0..2 handle RK stage wv ----
        if (wv < 3) {
            float tv = t00 + ((wv == 0) ? 0.f : (wv == 1) ? 0.5f : 0.75f) * dt;
            int cnt = 0;
            #pragma unroll
            for (int ch = 0; ch < 8; ++ch)
                cnt += __popcll(__ballot(tss[ch * 64 + lane] <= tv));
            int idx = min(max(cnt - 1, 0), TT - 2);
            if (lane < DD) {
                float frac = tv - tss[idx];
                size_t o = (size_t)idx * DD + lane;
                dvec[wv * 32 + lane] =
                    cbb[o] + frac * (2.f * ccb[o] + frac * 3.f * cdb[o]);
            }
        }
        // dvec consumed after 3 barriers inside q==0 — no extra barrier needed.

        #pragma unroll 1
        for (int q = 0; q < 3; ++q) {
            const int gen = s * 3 + q + 1;
            const int buf = gen & 1;
            const short* src16 = (q == 0) ? ybf : ybf;  // stage input mirror (updated in place)

            // ---- h1 = softplus(W0 @ y): MFMA, rows wv*16..+15 ----
            {
                f32x4 acc = {0.f, 0.f, 0.f, 0.f};
                #pragma unroll
                for (int K = 0; K < 4; ++K) {
                    short8 bk = *(const short8*)(src16 + K * 32 + quad * 8);
                    acc = __builtin_amdgcn_mfma_f32_16x16x32_bf16(w0f[K], bk, acc, 0, 0, 0);
                }
                if (qr == 0) {
                    short4 sp;
                    sp.x = bf16rne(softplus_f(acc[0] + fb0v.x));
                    sp.y = bf16rne(softplus_f(acc[1] + fb0v.y));
                    sp.z = bf16rne(softplus_f(acc[2] + fb0v.z));
                    sp.w = bf16rne(softplus_f(acc[3] + fb0v.w));
                    *(short4*)(h1bf + wv * 16 + quad * 4) = sp;
                }
            }
            __syncthreads();
            // ---- h2 = softplus(W1 @ h1): MFMA ----
            {
                f32x4 acc = {0.f, 0.f, 0.f, 0.f};
                #pragma unroll
                for (int K = 0; K < 4; ++K) {
                    short8 bk = *(const short8*)(h1bf + K * 32 + quad * 8);
                    acc = __builtin_amdgcn_mfma_f32_16x16x32_bf16(w1f[K], bk, acc, 0, 0, 0);
                }
                if (qr == 0) {
                    short4 sp;
                    sp.x = bf16rne(softplus_f(acc[0] + fb1v.x));
                    sp.y = bf16rne(softplus_f(acc[1] + fb1v.y));
                    sp.z = bf16rne(softplus_f(acc[2] + fb1v.z));
                    sp.w = bf16rne(softplus_f(acc[3] + fb1v.w));
                    *(short4*)(h2bf + wv * 16 + quad * 4) = sp;
                }
            }
            __syncthreads();

            // ---- big matvec: MFMA on register-resident W2; raw accs → rowbuf ----
            {
                short8 bfr[4];
                #pragma unroll
                for (int K = 0; K < 4; ++K)
                    bfr[K] = *(const short8*)(h2bf + K * 32 + quad * 8);
                #pragma unroll
                for (int gi = 0; gi < 4; ++gi) {
                    f32x4 a0 = {0.f, 0.f, 0.f, 0.f};
                    f32x4 a1 = {0.f, 0.f, 0.f, 0.f};
                    a0 = __builtin_amdgcn_mfma_f32_16x16x32_bf16(afr[gi][0], bfr[0], a0, 0, 0, 0);
                    a0 = __builtin_amdgcn_mfma_f32_16x16x32_bf16(afr[gi][1], bfr[1], a0, 0, 0, 0);
                    a0 = __builtin_amdgcn_mfma_f32_16x16x32_bf16(afr[gi][2], bfr[2], a0, 0, 0, 0);
                    a0 = __builtin_amdgcn_mfma_f32_16x16x32_bf16(afr[gi][3], bfr[3], a0, 0, 0, 0);
                    a1 = __builtin_amdgcn_mfma_f32_16x16x32_bf16(afr[gi][4], bfr[0], a1, 0, 0, 0);
                    a1 = __builtin_amdgcn_mfma_f32_16x16x32_bf16(afr[gi][5], bfr[1], a1, 0, 0, 0);
                    a1 = __builtin_amdgcn_mfma_f32_16x16x32_bf16(afr[gi][6], bfr[2], a1, 0, 0, 0);
                    a1 = __builtin_amdgcn_mfma_f32_16x16x32_bf16(afr[gi][7], bfr[3], a1, 0, 0, 0);
                    if (qr == 0) {
                        // C/D: col=qr(=0), d = t*16 + quad*4 + reg
                        float* rb = rowbuf + (wv * 4 + gi) * RSTR + quad * 4;
                        float4 v0, v1;
                        v0.x = a0[0]; v0.y = a0[1]; v0.z = a0[2]; v0.w = a0[3];
                        v1.x = a1[0]; v1.y = a1[1]; v1.z = a1[2]; v1.w = a1[3];
                        *(float4*)(rb)      = v0;
                        *(float4*)(rb + 16) = v1;
                    }
                }
            }
            __syncthreads();

            // ---- dedup epilogue: 2 tanh/thread, 16-lane reduce, publish ----
            {
                const int hl = tid >> 4;       // 0..31 local h
                const int d  = tid & 15;
                float v0 = rowbuf[hl * RSTR + d];
                float v1 = rowbuf[hl * RSTR + d + 16];
                float part = fast_tanh(v0 + fb2s[hl * 32 + d])      * dvec[q * 32 + d]
                           + fast_tanh(v1 + fb2s[hl * 32 + d + 16]) * dvec[q * 32 + d + 16];
                part += __shfl_xor(part, 1);
                part += __shfl_xor(part, 2);
                part += __shfl_xor(part, 4);
                part += __shfl_xor(part, 8);
                if (d == 0) {
                    unsigned long long pk =
                        ((unsigned long long)__float_as_uint(part * dt) << 32) | (unsigned)gen;
                    __hip_atomic_store(&kbuf[(size_t)(buf * BB + b) * HH + m * 32 + hl], pk,
                                       __ATOMIC_RELAXED, __HIP_MEMORY_SCOPE_AGENT);
                }
            }
            // ---- poll all 128 k-values (tag==gen), RK update, refresh bf16 mirror ----
            if (tid < HH) {
                unsigned long long v;
                for (;;) {
                    v = __hip_atomic_load(&kbuf[(size_t)(buf * BB + b) * HH + tid],
                                          __ATOMIC_RELAXED, __HIP_MEMORY_SCOPE_AGENT);
                    if ((unsigned)v == (unsigned)gen) break;
                    __builtin_amdgcn_s_sleep(1);
                }
                float kv = __uint_as_float((unsigned)(v >> 32));
                float nxt;
                if (q == 0)      { k1b[tid] = kv; nxt = ybuf[tid] + 0.5f  * kv; }
                else if (q == 1) { k2b[tid] = kv; nxt = ybuf[tid] + 0.75f * kv; }
                else {
                    nxt = ybuf[tid] + dt * ((2.f/9.f) * k1b[tid] + (1.f/3.f) * k2b[tid]
                                            + (4.f/9.f) * kv);
                    ybuf[tid] = nxt;
                }
                ybf[tid] = bf16rne(nxt);
            }
            __syncthreads();
        }

        // ---- readout (member 0, wave 0) on updated ybuf ----
        if (m == 0 && wv == 0) {
            float p = ybuf[lane] * lwa + ybuf[64 + lane] * lwb;
            p += __shfl_xor(p, 1);  p += __shfl_xor(p, 2);  p += __shfl_xor(p, 4);
            p += __shfl_xor(p, 8);  p += __shfl_xor(p, 16); p += __shfl_xor(p, 32);
            if (lane == 0) out[(size_t)b * TT + s] = 1.f / (1.f + __expf(-(p + lbv)));
        }
        t00 += dt;
    }
}

extern "C" void kernel_launch(void* const* d_in, const int* in_sizes, int n_in,
                              void* d_out, int out_size, void* d_ws, size_t ws_size,
                              hipStream_t stream) {
    const float* ts  = (const float*)d_in[0];
    const float* cdp = (const float*)d_in[1];
    const float* ccp = (const float*)d_in[2];
    const float* cbp = (const float*)d_in[3];
    const float* cap = (const float*)d_in[4];
    const float* iW0 = (const float*)d_in[5];
    const float* ib0 = (const float*)d_in[6];
    const float* iW1 = (const float*)d_in[7];
    const float* ib1 = (const float*)d_in[8];
    const float* iW2 = (const float*)d_in[9];
    const float* ib2 = (const float*)d_in[10];
    const float* fW0 = (const float*)d_in[11];
    const float* fb0 = (const float*)d_in[12];
    const float* fW1 = (const float*)d_in[13];
    const float* fb1 = (const float*)d_in[14];
    const float* fW2 = (const float*)d_in[15];
    const float* fb2 = (const float*)d_in[16];
    const float* lW  = (const float*)d_in[17];
    const float* lb  = (const float*)d_in[18];
    float* out = (float*)d_out;

    unsigned long long* kbuf = (unsigned long long*)d_ws;  // [2][64][128] u64 = 128 KiB
    hipMemsetAsync(d_ws, 0, 2 * BB * HH * sizeof(unsigned long long), stream);

    hipFuncSetAttribute((const void*)cde_kernel,
                        hipFuncAttributeMaxDynamicSharedMemorySize, SMEM_BYTES);
    hipLaunchKernelGGL(cde_kernel, dim3(256), dim3(NTHR), SMEM_BYTES, stream,
                       ts, cdp, ccp, cbp, cap, iW0, ib0, iW1, ib1, iW2, ib2,
                       fW0, fb0, fW1, fb1, fW2, fb2, lW, lb, kbuf, out);
}

// Round 6
// 4167.495 us; speedup vs baseline: 13.8770x; 1.9667x over previous
//
#include <hip/hip_runtime.h>
#include <hip/hip_bf16.h>

#define TT 512
#define BB 64
#define HH 128
#define WW 128
#define DD 32
#define NTHR 512

// LDS use is tiny now (~6 KB); request padded to 84 KiB to force exactly 1 WG/CU.
#define SMEM_BYTES 86016

typedef __attribute__((ext_vector_type(8))) short short8;
typedef __attribute__((ext_vector_type(4))) float f32x4;

__device__ __forceinline__ float softplus_f(float x) {
    // max(x,0) + log1p(exp(-|x|)) with native exp/log (err ~1e-7, absorbed by bf16 path)
    return fmaxf(x, 0.f) + __logf(1.f + __expf(-fabsf(x)));
}
__device__ __forceinline__ float fast_tanh(float x) {
    float ax = fabsf(x);
    float e  = __expf(-2.f * ax);
    float r  = (1.f - e) * __builtin_amdgcn_rcpf(1.f + e);
    return copysignf(r, x);
}
__device__ __forceinline__ short bf16rne(float x) {
    unsigned u = __float_as_uint(x);
    u += 0x7fffu + ((u >> 16) & 1u);
    return (short)(u >> 16);
}

__global__ __launch_bounds__(NTHR, 2)
void cde_kernel(const float* __restrict__ ts,
                const float* __restrict__ cd, const float* __restrict__ cc,
                const float* __restrict__ cb, const float* __restrict__ ca,
                const float* __restrict__ iW0, const float* __restrict__ ib0,
                const float* __restrict__ iW1, const float* __restrict__ ib1,
                const float* __restrict__ iW2, const float* __restrict__ ib2,
                const float* __restrict__ fW0, const float* __restrict__ fb0,
                const float* __restrict__ fW1, const float* __restrict__ fb1,
                const float* __restrict__ fW2, const float* __restrict__ fb2,
                const float* __restrict__ lW, const float* __restrict__ lb,
                unsigned long long* kbuf,
                float* __restrict__ out)
{
    extern __shared__ float sm[];
    float* tss  = sm;                  // [512]
    float* ybuf = tss + TT;            // [128] fp32 state (for readout)
    float* dvec = ybuf + 128;          // [96]
    float* scr  = dvec + 96;           // [256] init-MLP scratch
    short* ybf  = (short*)(scr + 256); // [128] bf16 y mirror
    short* h1bf = ybf + 128;           // [128]
    short* h2bf = h1bf + 128;          // [128]

    const int tid  = threadIdx.x;
    const int lane = tid & 63;
    const int wv   = tid >> 6;               // 0..7
    const int quad = lane >> 4;              // 0..3
    const int qr   = lane & 15;              // 0..15
    const int b    = blockIdx.x & 63;        // batch; members ≡ b (mod 8) → same XCD class
    const int m    = blockIdx.x >> 6;        // member 0..3

    // epilogue combo decode (per lane): gi=cg, tile=ct, r-half=rh
    const int cg = qr & 3;
    const int ct = (qr >> 2) & 1;
    const int rh = qr >> 3;
    const int dbase = ct * 16 + quad * 4 + rh * 2;   // d index of this lane's 2 values

    for (int i = tid; i < TT; i += NTHR) tss[i] = ts[(size_t)b * TT + i];

    // ---- register-resident weights (loop-invariant bf16 A-fragments) ----
    short8 afr[4][8];
    #pragma unroll
    for (int gi = 0; gi < 4; ++gi) {
        int g = m * 32 + wv * 4 + gi;
        #pragma unroll
        for (int t = 0; t < 2; ++t)
        #pragma unroll
        for (int K = 0; K < 4; ++K) {
            int row = g * 32 + t * 16 + qr;
            int col = K * 32 + quad * 8;
            const float* src = fW2 + (size_t)row * WW + col;
            short8 v;
            #pragma unroll
            for (int j = 0; j < 8; ++j) v[j] = bf16rne(src[j]);
            afr[gi][t * 4 + K] = v;
        }
    }
    short8 w0f[4], w1f[4];
    #pragma unroll
    for (int K = 0; K < 4; ++K) {
        int row = wv * 16 + qr;
        int col = K * 32 + quad * 8;
        const float* s0 = fW0 + (size_t)row * HH + col;
        const float* s1 = fW1 + (size_t)row * WW + col;
        short8 v0, v1;
        #pragma unroll
        for (int j = 0; j < 8; ++j) { v0[j] = bf16rne(s0[j]); v1[j] = bf16rne(s1[j]); }
        w0f[K] = v0; w1f[K] = v1;
    }
    // per-lane bias registers
    const float fb0r = fb0[wv * 16 + quad * 4 + cg];
    const float fb1r = fb1[wv * 16 + quad * 4 + cg];
    const int   hrow = m * 32 + wv * 4 + cg;
    const float fb2a = fb2[hrow * 32 + dbase];
    const float fb2b = fb2[hrow * 32 + dbase + 1];

    __syncthreads();

    const float dt = tss[1] - tss[0];
    float t00 = tss[0];
    const size_t cstride = (size_t)(TT - 1) * DD;
    const float* cdb = cd + (size_t)b * cstride;
    const float* ccb = cc + (size_t)b * cstride;
    const float* cbb = cb + (size_t)b * cstride;

    // ---- initial_mlp (replicated, one-time, fp32) ----
    if (tid < HH) {
        const float* a0 = ca + (size_t)b * cstride;
        float acc = ib0[tid];
        #pragma unroll
        for (int k = 0; k < DD; ++k) acc += iW0[tid * DD + k] * a0[k];
        scr[tid] = fmaxf(acc, 0.f);
    }
    __syncthreads();
    if (tid < HH) {
        float acc = ib1[tid];
        for (int k = 0; k < WW; ++k) acc += iW1[tid * WW + k] * scr[k];
        scr[128 + tid] = fmaxf(acc, 0.f);
    }
    __syncthreads();
    float yreg = 0.f, k1r = 0.f, k2r = 0.f;
    if (tid < HH) {
        float acc = ib2[tid];
        for (int k = 0; k < WW; ++k) acc += iW2[tid * WW + k] * scr[128 + k];
        yreg = acc;
        ybuf[tid] = acc;
        ybf[tid]  = bf16rne(acc);
    }
    __syncthreads();

    float lwa = 0.f, lwb = 0.f, lbv = 0.f;
    if (wv == 0) { lwa = lW[lane]; lwb = lW[64 + lane]; lbv = lb[0]; }

    for (int s = 0; s < TT; ++s) {
        // ---- searchsorted + dvec: waves 0..2 handle RK stage wv (consumed after 2 barriers) ----
        if (wv < 3) {
            float tv = t00 + ((wv == 0) ? 0.f : (wv == 1) ? 0.5f : 0.75f) * dt;
            int cnt = 0;
            #pragma unroll
            for (int ch = 0; ch < 8; ++ch)
                cnt += __popcll(__ballot(tss[ch * 64 + lane] <= tv));
            int idx = min(max(cnt - 1, 0), TT - 2);
            if (lane < DD) {
                float frac = tv - tss[idx];
                size_t o = (size_t)idx * DD + lane;
                dvec[wv * 32 + lane] =
                    cbb[o] + frac * (2.f * ccb[o] + frac * 3.f * cdb[o]);
            }
        }

        #pragma unroll 1
        for (int q = 0; q < 3; ++q) {
            const int gen = s * 3 + q + 1;
            const int buf = gen & 1;

            // ---- h1 = softplus(W0 @ y): 2 indep MFMA chains; dedup softplus (qr<4) ----
            {
                f32x4 aA = {0.f, 0.f, 0.f, 0.f}, aB = {0.f, 0.f, 0.f, 0.f};
                short8 b0 = *(const short8*)(ybf + 0 * 32 + quad * 8);
                short8 b1 = *(const short8*)(ybf + 1 * 32 + quad * 8);
                short8 b2 = *(const short8*)(ybf + 2 * 32 + quad * 8);
                short8 b3 = *(const short8*)(ybf + 3 * 32 + quad * 8);
                aA = __builtin_amdgcn_mfma_f32_16x16x32_bf16(w0f[0], b0, aA, 0, 0, 0);
                aB = __builtin_amdgcn_mfma_f32_16x16x32_bf16(w0f[1], b1, aB, 0, 0, 0);
                aA = __builtin_amdgcn_mfma_f32_16x16x32_bf16(w0f[2], b2, aA, 0, 0, 0);
                aB = __builtin_amdgcn_mfma_f32_16x16x32_bf16(w0f[3], b3, aB, 0, 0, 0);
                f32x4 h = aA + aB;
                if (qr < 4) {
                    float v = (qr & 1) ? ((qr & 2) ? h[3] : h[1])
                                       : ((qr & 2) ? h[2] : h[0]);
                    h1bf[wv * 16 + quad * 4 + qr] = bf16rne(softplus_f(v + fb0r));
                }
            }
            __syncthreads();
            // ---- h2 = softplus(W1 @ h1) ----
            {
                f32x4 aA = {0.f, 0.f, 0.f, 0.f}, aB = {0.f, 0.f, 0.f, 0.f};
                short8 b0 = *(const short8*)(h1bf + 0 * 32 + quad * 8);
                short8 b1 = *(const short8*)(h1bf + 1 * 32 + quad * 8);
                short8 b2 = *(const short8*)(h1bf + 2 * 32 + quad * 8);
                short8 b3 = *(const short8*)(h1bf + 3 * 32 + quad * 8);
                aA = __builtin_amdgcn_mfma_f32_16x16x32_bf16(w1f[0], b0, aA, 0, 0, 0);
                aB = __builtin_amdgcn_mfma_f32_16x16x32_bf16(w1f[1], b1, aB, 0, 0, 0);
                aA = __builtin_amdgcn_mfma_f32_16x16x32_bf16(w1f[2], b2, aA, 0, 0, 0);
                aB = __builtin_amdgcn_mfma_f32_16x16x32_bf16(w1f[3], b3, aB, 0, 0, 0);
                f32x4 h = aA + aB;
                if (qr < 4) {
                    float v = (qr & 1) ? ((qr & 2) ? h[3] : h[1])
                                       : ((qr & 2) ? h[2] : h[0]);
                    h2bf[wv * 16 + quad * 4 + qr] = bf16rne(softplus_f(v + fb1r));
                }
            }
            __syncthreads();

            // ---- W2 MFMA + in-register dedup epilogue + publish (no barrier inside) ----
            {
                short8 bfr[4];
                #pragma unroll
                for (int K = 0; K < 4; ++K)
                    bfr[K] = *(const short8*)(h2bf + K * 32 + quad * 8);
                f32x4 A0[4], A1[4];
                #pragma unroll
                for (int gi = 0; gi < 4; ++gi) {
                    f32x4 a0 = {0.f, 0.f, 0.f, 0.f};
                    f32x4 a1 = {0.f, 0.f, 0.f, 0.f};
                    a0 = __builtin_amdgcn_mfma_f32_16x16x32_bf16(afr[gi][0], bfr[0], a0, 0, 0, 0);
                    a0 = __builtin_amdgcn_mfma_f32_16x16x32_bf16(afr[gi][1], bfr[1], a0, 0, 0, 0);
                    a0 = __builtin_amdgcn_mfma_f32_16x16x32_bf16(afr[gi][2], bfr[2], a0, 0, 0, 0);
                    a0 = __builtin_amdgcn_mfma_f32_16x16x32_bf16(afr[gi][3], bfr[3], a0, 0, 0, 0);
                    a1 = __builtin_amdgcn_mfma_f32_16x16x32_bf16(afr[gi][4], bfr[0], a1, 0, 0, 0);
                    a1 = __builtin_amdgcn_mfma_f32_16x16x32_bf16(afr[gi][5], bfr[1], a1, 0, 0, 0);
                    a1 = __builtin_amdgcn_mfma_f32_16x16x32_bf16(afr[gi][6], bfr[2], a1, 0, 0, 0);
                    a1 = __builtin_amdgcn_mfma_f32_16x16x32_bf16(afr[gi][7], bfr[3], a1, 0, 0, 0);
                    A0[gi] = a0; A1[gi] = a1;
                }
                // select this lane's combo (cg over gi, ct over tile) — cndmask tree
                f32x4 s0a = (cg & 1) ? A0[1] : A0[0];
                f32x4 s0b = (cg & 1) ? A0[3] : A0[2];
                f32x4 s0  = (cg & 2) ? s0b : s0a;
                f32x4 s1a = (cg & 1) ? A1[1] : A1[0];
                f32x4 s1b = (cg & 1) ? A1[3] : A1[2];
                f32x4 s1  = (cg & 2) ? s1b : s1a;
                f32x4 st  = ct ? s1 : s0;
                float va = rh ? st[2] : st[0];
                float vb = rh ? st[3] : st[1];
                float2 dv = *(const float2*)(dvec + q * 32 + dbase);
                float p = fast_tanh(va + fb2a) * dv.x + fast_tanh(vb + fb2b) * dv.y;
                p += __shfl_xor(p, 8);    // r-halves
                p += __shfl_xor(p, 4);    // tiles
                p += __shfl_xor(p, 16);   // quad
                p += __shfl_xor(p, 32);
                if (lane < 4) {
                    unsigned long long pk =
                        ((unsigned long long)__float_as_uint(p * dt) << 32) | (unsigned)gen;
                    __hip_atomic_store(&kbuf[(size_t)(buf * BB + b) * HH + m * 32 + wv * 4 + lane],
                                       pk, __ATOMIC_RELAXED, __HIP_MEMORY_SCOPE_AGENT);
                }
            }
            // ---- poll all 128 k (tag==gen), RK in registers, refresh mirrors ----
            if (tid < HH) {
                unsigned long long v;
                int it = 0;
                for (;;) {
                    v = __hip_atomic_load(&kbuf[(size_t)(buf * BB + b) * HH + tid],
                                          __ATOMIC_RELAXED, __HIP_MEMORY_SCOPE_AGENT);
                    if ((unsigned)v == (unsigned)gen) break;
                    if (it < 8) __builtin_amdgcn_s_sleep(1);
                    else        __builtin_amdgcn_s_sleep(8);
                    ++it;
                }
                float kv = __uint_as_float((unsigned)(v >> 32));
                float nxt;
                if (q == 0)      { k1r = kv; nxt = yreg + 0.5f  * kv; }
                else if (q == 1) { k2r = kv; nxt = yreg + 0.75f * kv; }
                else {
                    nxt = yreg + dt * ((2.f/9.f) * k1r + (1.f/3.f) * k2r + (4.f/9.f) * kv);
                    yreg = nxt;
                    ybuf[tid] = nxt;
                }
                ybf[tid] = bf16rne(nxt);
            }
            __syncthreads();
        }

        // ---- readout (member 0, wave 0) ----
        if (m == 0 && wv == 0) {
            float p = ybuf[lane] * lwa + ybuf[64 + lane] * lwb;
            p += __shfl_xor(p, 1);  p += __shfl_xor(p, 2);  p += __shfl_xor(p, 4);
            p += __shfl_xor(p, 8);  p += __shfl_xor(p, 16); p += __shfl_xor(p, 32);
            if (lane == 0) out[(size_t)b * TT + s] = 1.f / (1.f + __expf(-(p + lbv)));
        }
        t00 += dt;
    }
}

extern "C" void kernel_launch(void* const* d_in, const int* in_sizes, int n_in,
                              void* d_out, int out_size, void* d_ws, size_t ws_size,
                              hipStream_t stream) {
    const float* ts  = (const float*)d_in[0];
    const float* cdp = (const float*)d_in[1];
    const float* ccp = (const float*)d_in[2];
    const float* cbp = (const float*)d_in[3];
    const float* cap = (const float*)d_in[4];
    const float* iW0 = (const float*)d_in[5];
    const float* ib0 = (const float*)d_in[6];
    const float* iW1 = (const float*)d_in[7];
    const float* ib1 = (const float*)d_in[8];
    const float* iW2 = (const float*)d_in[9];
    const float* ib2 = (const float*)d_in[10];
    const float* fW0 = (const float*)d_in[11];
    const float* fb0 = (const float*)d_in[12];
    const float* fW1 = (const float*)d_in[13];
    const float* fb1 = (const float*)d_in[14];
    const float* fW2 = (const float*)d_in[15];
    const float* fb2 = (const float*)d_in[16];
    const float* lW  = (const float*)d_in[17];
    const float* lb  = (const float*)d_in[18];
    float* out = (float*)d_out;

    unsigned long long* kbuf = (unsigned long long*)d_ws;  // [2][64][128] u64 = 128 KiB
    hipMemsetAsync(d_ws, 0, 2 * BB * HH * sizeof(unsigned long long), stream);

    hipFuncSetAttribute((const void*)cde_kernel,
                        hipFuncAttributeMaxDynamicSharedMemorySize, SMEM_BYTES);
    hipLaunchKernelGGL(cde_kernel, dim3(256), dim3(NTHR), SMEM_BYTES, stream,
                       ts, cdp, ccp, cbp, cap, iW0, ib0, iW1, ib1, iW2, ib2,
                       fW0, fb0, fW1, fb1, fW2, fb2, lW, lb, kbuf, out);
}